// Round 3
// baseline (1500.982 us; speedup 1.0000x reference)
//
#include <hip/hip_runtime.h>

#define N_NODES 100000
#define N_EDGES 1600000
#define IN_FEAT 128
#define OUT_FEAT 64
#define SLOPE 0.22916666666666666f  // (1/8 + 1/3)/2 = 11/48

#define NPB 128            // nodes per bucket
#define NB 782             // ceil(N_NODES / NPB)
#define BIN_CHUNK 8192     // edges per binning block
#define EPT 32             // edges per thread in binning (BIN_CHUNK/256)

// ---------------------------------------------------------------------------
// Bucket histogram: LDS-binned per block, one global atomic per bucket/block.
// ---------------------------------------------------------------------------
__global__ __launch_bounds__(256) void bhist_kernel(const int* __restrict__ dst,
                                                    int* __restrict__ bhist) {
    __shared__ int lh[NB];
    for (int i = threadIdx.x; i < NB; i += 256) lh[i] = 0;
    __syncthreads();
    const int base = blockIdx.x * 2048;
#pragma unroll
    for (int i = 0; i < 8; ++i) {
        const int e = base + i * 256 + threadIdx.x;
        if (e < N_EDGES) atomicAdd(&lh[dst[e] >> 7], 1);
    }
    __syncthreads();
    for (int i = threadIdx.x; i < NB; i += 256)
        if (lh[i]) atomicAdd(&bhist[i], lh[i]);
}

// ---------------------------------------------------------------------------
// Exclusive scan of 782 bucket counts (single block). Writes bbase[NB+1]
// and initializes bcur = bbase.
// ---------------------------------------------------------------------------
__global__ __launch_bounds__(256) void bscan_kernel(const int* __restrict__ bhist,
                                                    int* __restrict__ bbase,
                                                    int* __restrict__ bcur) {
    __shared__ int wsum[4];
    const int t = threadIdx.x;
    int v[4];
    int s = 0;
#pragma unroll
    for (int i = 0; i < 4; ++i) {
        const int idx = t * 4 + i;
        v[i] = s;  // exclusive prefix within this thread's segment
        s += (idx < NB) ? bhist[idx] : 0;
    }
    const int lane = t & 63, wave = t >> 6;
    int x = s;  // inclusive wave scan of thread totals
#pragma unroll
    for (int off = 1; off < 64; off <<= 1) {
        int y = __shfl_up(x, off);
        if (lane >= off) x += y;
    }
    if (lane == 63) wsum[wave] = x;
    __syncthreads();
    int wbase = 0;
    for (int w = 0; w < 4; ++w)
        if (w < wave) wbase += wsum[w];
    const int tbase = wbase + x - s;
#pragma unroll
    for (int i = 0; i < 4; ++i) {
        const int idx = t * 4 + i;
        if (idx < NB) {
            bbase[idx] = tbase + v[i];
            bcur[idx]  = tbase + v[i];
        }
    }
    if (t == 255) bbase[NB] = wbase + x;  // total = N_EDGES
}

// ---------------------------------------------------------------------------
// Binning: each block takes 8192 edges, assigns local ranks via LDS counters,
// claims one contiguous global run per bucket, writes packed edges
// ((dst&127)<<17 | src) into dense per-block runs -> low write amplification.
// ---------------------------------------------------------------------------
__global__ __launch_bounds__(256) void binning_kernel(const int* __restrict__ src,
                                                      const int* __restrict__ dst,
                                                      int* __restrict__ bcur,
                                                      int* __restrict__ pairs) {
    __shared__ int cnt[NB];
    __shared__ int gbase[NB];
    for (int i = threadIdx.x; i < NB; i += 256) cnt[i] = 0;
    __syncthreads();
    const int base = blockIdx.x * BIN_CHUNK;
    int bl[EPT];  // (bucket<<13) | local_rank, or -1
    int vp[EPT];  // packed payload
#pragma unroll
    for (int i = 0; i < EPT; ++i) {
        const int e = base + i * 256 + threadIdx.x;
        if (e < N_EDGES) {
            const int d = dst[e];
            const int b = d >> 7;
            const int lpos = atomicAdd(&cnt[b], 1);
            bl[i] = (b << 13) | lpos;
            vp[i] = ((d & 127) << 17) | src[e];
        } else {
            bl[i] = -1;
        }
    }
    __syncthreads();
    for (int i = threadIdx.x; i < NB; i += 256) {
        const int c = cnt[i];
        gbase[i] = c ? atomicAdd(&bcur[i], c) : 0;
    }
    __syncthreads();
#pragma unroll
    for (int i = 0; i < EPT; ++i) {
        if (bl[i] >= 0) {
            const int b = bl[i] >> 13, lpos = bl[i] & 8191;
            pairs[gbase[b] + lpos] = vp[i];
        }
    }
}

// ---------------------------------------------------------------------------
// Aggregation + fused rrelu: one block per bucket, 32 KB LDS accumulator
// (128 rows x 64 cols f32). Wave-per-edge, lane=column; gathers h[src] rows
// (h = 25.6 MB -> L3-resident), LDS atomic add (2 lanes/bank -> free),
// dense 32 KB output write per block.
// ---------------------------------------------------------------------------
__global__ __launch_bounds__(256) void agg_rrelu_kernel(const float* __restrict__ h,
                                                        const int* __restrict__ pairs,
                                                        const int* __restrict__ bbase,
                                                        float* __restrict__ out) {
    __shared__ float acc[NPB * OUT_FEAT];  // 32 KB
    __shared__ int pbuf[1024];
    float4* acc4 = (float4*)acc;
#pragma unroll
    for (int i = 0; i < 8; ++i)
        acc4[threadIdx.x + i * 256] = make_float4(0.f, 0.f, 0.f, 0.f);

    const int b = blockIdx.x;
    const int beg = bbase[b], end = bbase[b + 1];
    const int wave = threadIdx.x >> 6, c = threadIdx.x & 63;

    for (int cb = beg; cb < end; cb += 1024) {
        const int m = min(1024, end - cb);
        __syncthreads();  // previous chunk fully consumed (also covers acc init)
        for (int i = threadIdx.x; i < m; i += 256) pbuf[i] = pairs[cb + i];
        __syncthreads();
        const int lo = wave * 256;
        const int hi = min(lo + 256, m);
        int j = lo;
        for (; j + 4 <= hi; j += 4) {
            const int p0 = pbuf[j], p1 = pbuf[j + 1], p2 = pbuf[j + 2], p3 = pbuf[j + 3];
            const float v0 = h[(size_t)(p0 & 0x1FFFF) * OUT_FEAT + c];
            const float v1 = h[(size_t)(p1 & 0x1FFFF) * OUT_FEAT + c];
            const float v2 = h[(size_t)(p2 & 0x1FFFF) * OUT_FEAT + c];
            const float v3 = h[(size_t)(p3 & 0x1FFFF) * OUT_FEAT + c];
            atomicAdd(&acc[(p0 >> 17) * OUT_FEAT + c], v0);
            atomicAdd(&acc[(p1 >> 17) * OUT_FEAT + c], v1);
            atomicAdd(&acc[(p2 >> 17) * OUT_FEAT + c], v2);
            atomicAdd(&acc[(p3 >> 17) * OUT_FEAT + c], v3);
        }
        for (; j < hi; ++j) {
            const int p = pbuf[j];
            const float v = h[(size_t)(p & 0x1FFFF) * OUT_FEAT + c];
            atomicAdd(&acc[(p >> 17) * OUT_FEAT + c], v);
        }
    }
    __syncthreads();

    const int node0 = b * NPB;
#pragma unroll
    for (int i = 0; i < 8; ++i) {
        const int idx = threadIdx.x + i * 256;  // float4 index within bucket
        const int node = node0 + (idx >> 4);    // 16 float4 per row
        if (node < N_NODES) {
            float4 v = acc4[idx];
            v.x = v.x >= 0.f ? v.x : v.x * SLOPE;
            v.y = v.y >= 0.f ? v.y : v.y * SLOPE;
            v.z = v.z >= 0.f ? v.z : v.z * SLOPE;
            v.w = v.w >= 0.f ? v.w : v.w * SLOPE;
            ((float4*)out)[(size_t)node * 16 + (idx & 15)] = v;
        }
    }
}

// ---------------------------------------------------------------------------
// GEMM1: feat[N,128] @ w1[128,64]. 16 rows/block, 4 rows/thread.
// ---------------------------------------------------------------------------
__global__ __launch_bounds__(256) void gemm1_kernel(const float* __restrict__ feat,
                                                    const float* __restrict__ w1,
                                                    float* __restrict__ h1) {
    __shared__ float w[IN_FEAT * OUT_FEAT];  // 32 KB
    __shared__ float f[16 * IN_FEAT];        // 8 KB
    const int tid = threadIdx.x;

    const float4* w4 = (const float4*)w1;
    float4* wl = (float4*)w;
#pragma unroll
    for (int i = 0; i < 8; ++i) wl[tid + i * 256] = w4[tid + i * 256];

    const int row0 = blockIdx.x * 16;
    const float4* fg = (const float4*)(feat + (size_t)row0 * IN_FEAT);
    float4* fl = (float4*)f;
#pragma unroll
    for (int i = 0; i < 2; ++i) fl[tid + i * 256] = fg[tid + i * 256];
    __syncthreads();

    const int c = tid & 63;
    const int rg = tid >> 6;
    float acc0 = 0.f, acc1 = 0.f, acc2 = 0.f, acc3 = 0.f;
    const float4* fv = (const float4*)f;
#pragma unroll
    for (int k = 0; k < IN_FEAT; k += 4) {
        const float wa = w[(k + 0) * OUT_FEAT + c];
        const float wb = w[(k + 1) * OUT_FEAT + c];
        const float wc = w[(k + 2) * OUT_FEAT + c];
        const float wd = w[(k + 3) * OUT_FEAT + c];
        float4 a = fv[((rg * 4 + 0) * IN_FEAT + k) >> 2];
        acc0 += a.x * wa + a.y * wb + a.z * wc + a.w * wd;
        float4 bb = fv[((rg * 4 + 1) * IN_FEAT + k) >> 2];
        acc1 += bb.x * wa + bb.y * wb + bb.z * wc + bb.w * wd;
        float4 d = fv[((rg * 4 + 2) * IN_FEAT + k) >> 2];
        acc2 += d.x * wa + d.y * wb + d.z * wc + d.w * wd;
        float4 e = fv[((rg * 4 + 3) * IN_FEAT + k) >> 2];
        acc3 += e.x * wa + e.y * wb + e.z * wc + e.w * wd;
    }
    h1[(size_t)(row0 + rg * 4 + 0) * OUT_FEAT + c] = acc0;
    h1[(size_t)(row0 + rg * 4 + 1) * OUT_FEAT + c] = acc1;
    h1[(size_t)(row0 + rg * 4 + 2) * OUT_FEAT + c] = acc2;
    h1[(size_t)(row0 + rg * 4 + 3) * OUT_FEAT + c] = acc3;
}

// ---------------------------------------------------------------------------
// GEMM2: agg1[N,64] @ w2[64,64] (input already rrelu'd by agg kernel)
// ---------------------------------------------------------------------------
__global__ __launch_bounds__(256) void gemm2_kernel(const float* __restrict__ agg1,
                                                    const float* __restrict__ w2,
                                                    float* __restrict__ h2) {
    __shared__ float w[OUT_FEAT * OUT_FEAT];  // 16 KB
    __shared__ float f[16 * OUT_FEAT];        // 4 KB
    const int tid = threadIdx.x;

    const float4* w4 = (const float4*)w2;
    float4* wl = (float4*)w;
#pragma unroll
    for (int i = 0; i < 4; ++i) wl[tid + i * 256] = w4[tid + i * 256];

    const int row0 = blockIdx.x * 16;
    const float4* fg = (const float4*)(agg1 + (size_t)row0 * OUT_FEAT);
    ((float4*)f)[tid] = fg[tid];
    __syncthreads();

    const int c = tid & 63;
    const int rg = tid >> 6;
    float acc0 = 0.f, acc1 = 0.f, acc2 = 0.f, acc3 = 0.f;
    const float4* fv = (const float4*)f;
#pragma unroll
    for (int k = 0; k < OUT_FEAT; k += 4) {
        const float wa = w[(k + 0) * OUT_FEAT + c];
        const float wb = w[(k + 1) * OUT_FEAT + c];
        const float wc = w[(k + 2) * OUT_FEAT + c];
        const float wd = w[(k + 3) * OUT_FEAT + c];
        float4 a = fv[((rg * 4 + 0) * OUT_FEAT + k) >> 2];
        acc0 += a.x * wa + a.y * wb + a.z * wc + a.w * wd;
        float4 bb = fv[((rg * 4 + 1) * OUT_FEAT + k) >> 2];
        acc1 += bb.x * wa + bb.y * wb + bb.z * wc + bb.w * wd;
        float4 d = fv[((rg * 4 + 2) * OUT_FEAT + k) >> 2];
        acc2 += d.x * wa + d.y * wb + d.z * wc + d.w * wd;
        float4 e = fv[((rg * 4 + 3) * OUT_FEAT + k) >> 2];
        acc3 += e.x * wa + e.y * wb + e.z * wc + e.w * wd;
    }
    h2[(size_t)(row0 + rg * 4 + 0) * OUT_FEAT + c] = acc0;
    h2[(size_t)(row0 + rg * 4 + 1) * OUT_FEAT + c] = acc1;
    h2[(size_t)(row0 + rg * 4 + 2) * OUT_FEAT + c] = acc2;
    h2[(size_t)(row0 + rg * 4 + 3) * OUT_FEAT + c] = acc3;
}

extern "C" void kernel_launch(void* const* d_in, const int* in_sizes, int n_in,
                              void* d_out, int out_size, void* d_ws, size_t ws_size,
                              hipStream_t stream) {
    const float* feat = (const float*)d_in[0];
    const int*   src  = (const int*)d_in[1];
    const int*   dst  = (const int*)d_in[2];
    const float* w1   = (const float*)d_in[3];
    const float* w2   = (const float*)d_in[4];
    float* out = (float*)d_out;

    // workspace layout
    float* h     = (float*)d_ws;                           // 25.6 MB
    int*   pairs = (int*)(h + (size_t)N_NODES * OUT_FEAT); // 6.4 MB
    int*   bhist = pairs + N_EDGES;                        // NB
    int*   bbase = bhist + NB;                             // NB+1
    int*   bcur  = bbase + NB + 1;                         // NB

    // ---- build bucketed edge list (once; reused for both layers) ----
    hipMemsetAsync(bhist, 0, NB * sizeof(int), stream);
    bhist_kernel<<<(N_EDGES + 2047) / 2048, 256, 0, stream>>>(dst, bhist);
    bscan_kernel<<<1, 256, 0, stream>>>(bhist, bbase, bcur);
    binning_kernel<<<(N_EDGES + BIN_CHUNK - 1) / BIN_CHUNK, 256, 0, stream>>>(
        src, dst, bcur, pairs);

    // ---- layer 1 ----
    gemm1_kernel<<<N_NODES / 16, 256, 0, stream>>>(feat, w1, h);
    agg_rrelu_kernel<<<NB, 256, 0, stream>>>(h, pairs, bbase, out);

    // ---- layer 2 ----
    gemm2_kernel<<<N_NODES / 16, 256, 0, stream>>>(out, w2, h);
    agg_rrelu_kernel<<<NB, 256, 0, stream>>>(h, pairs, bbase, out);
}

// Round 4
// 268.073 us; speedup vs baseline: 5.5992x; 5.5992x over previous
//
#include <hip/hip_runtime.h>

#define N_NODES 100000
#define N_EDGES 1600000
#define IN_FEAT 128
#define OUT_FEAT 64
#define SLOPE 0.22916666666666666f  // (1/8 + 1/3)/2 = 11/48

#define NPB 128            // nodes per bucket
#define NB 782             // ceil(N_NODES / NPB)
#define BIN_CHUNK 8192     // edges per binning block
#define EPT 32             // edges per thread in binning (BIN_CHUNK/256)

__device__ __forceinline__ ushort f2bf(float x) {
    unsigned u = __float_as_uint(x);
    u += 0x7FFFu + ((u >> 16) & 1u);  // round to nearest even
    return (ushort)(u >> 16);
}
__device__ __forceinline__ float bf2f(ushort v) {
    return __uint_as_float((unsigned)v << 16);
}

// ---------------------------------------------------------------------------
// Bucket histogram: LDS-binned per block, one global atomic per bucket/block.
// ---------------------------------------------------------------------------
__global__ __launch_bounds__(256) void bhist_kernel(const int* __restrict__ dst,
                                                    int* __restrict__ bhist) {
    __shared__ int lh[NB];
    for (int i = threadIdx.x; i < NB; i += 256) lh[i] = 0;
    __syncthreads();
    const int base = blockIdx.x * 2048;
#pragma unroll
    for (int i = 0; i < 8; ++i) {
        const int e = base + i * 256 + threadIdx.x;
        if (e < N_EDGES) atomicAdd(&lh[dst[e] >> 7], 1);
    }
    __syncthreads();
    for (int i = threadIdx.x; i < NB; i += 256)
        if (lh[i]) atomicAdd(&bhist[i], lh[i]);
}

// ---------------------------------------------------------------------------
// Exclusive scan of 782 bucket counts (single block) -> bbase[NB+1], bcur.
// ---------------------------------------------------------------------------
__global__ __launch_bounds__(256) void bscan_kernel(const int* __restrict__ bhist,
                                                    int* __restrict__ bbase,
                                                    int* __restrict__ bcur) {
    __shared__ int wsum[4];
    const int t = threadIdx.x;
    int v[4];
    int s = 0;
#pragma unroll
    for (int i = 0; i < 4; ++i) {
        const int idx = t * 4 + i;
        v[i] = s;
        s += (idx < NB) ? bhist[idx] : 0;
    }
    const int lane = t & 63, wave = t >> 6;
    int x = s;
#pragma unroll
    for (int off = 1; off < 64; off <<= 1) {
        int y = __shfl_up(x, off);
        if (lane >= off) x += y;
    }
    if (lane == 63) wsum[wave] = x;
    __syncthreads();
    int wbase = 0;
    for (int w = 0; w < 4; ++w)
        if (w < wave) wbase += wsum[w];
    const int tbase = wbase + x - s;
#pragma unroll
    for (int i = 0; i < 4; ++i) {
        const int idx = t * 4 + i;
        if (idx < NB) {
            bbase[idx] = tbase + v[i];
            bcur[idx]  = tbase + v[i];
        }
    }
    if (t == 255) bbase[NB] = wbase + x;  // == N_EDGES
}

// ---------------------------------------------------------------------------
// Binning pass 1: dense per-block runs of packed ((dst&127)<<17 | src).
// ---------------------------------------------------------------------------
__global__ __launch_bounds__(256) void binning_kernel(const int* __restrict__ src,
                                                      const int* __restrict__ dst,
                                                      int* __restrict__ bcur,
                                                      int* __restrict__ pairs) {
    __shared__ int cnt[NB];
    __shared__ int gbase[NB];
    for (int i = threadIdx.x; i < NB; i += 256) cnt[i] = 0;
    __syncthreads();
    const int base = blockIdx.x * BIN_CHUNK;
    int bl[EPT];
    int vp[EPT];
#pragma unroll
    for (int i = 0; i < EPT; ++i) {
        const int e = base + i * 256 + threadIdx.x;
        if (e < N_EDGES) {
            const int d = dst[e];
            const int b = d >> 7;
            const int lpos = atomicAdd(&cnt[b], 1);
            bl[i] = (b << 13) | lpos;
            vp[i] = ((d & 127) << 17) | src[e];
        } else {
            bl[i] = -1;
        }
    }
    __syncthreads();
    for (int i = threadIdx.x; i < NB; i += 256) {
        const int c = cnt[i];
        gbase[i] = c ? atomicAdd(&bcur[i], c) : 0;
    }
    __syncthreads();
#pragma unroll
    for (int i = 0; i < EPT; ++i) {
        if (bl[i] >= 0) {
            const int b = bl[i] >> 13, lpos = bl[i] & 8191;
            pairs[gbase[b] + lpos] = vp[i];
        }
    }
}

// ---------------------------------------------------------------------------
// Binning pass 2: per-bucket counting sort -> per-node CSR segments.
// One block per bucket; all writes land in the bucket's own ~8 KB csr window
// (write amplification ~1). Also emits per-node offsets nptr (NB*NPB+1 slots;
// ghost slots past N_NODES have zero counts so nptr stays monotone).
// ---------------------------------------------------------------------------
__global__ __launch_bounds__(256) void sort2_kernel(const int* __restrict__ pairs,
                                                    const int* __restrict__ bbase,
                                                    int* __restrict__ csr,
                                                    int* __restrict__ nptr) {
    __shared__ int cnt[NPB];
    __shared__ int cur[NPB];
    __shared__ int wtot;
    const int b = blockIdx.x;
    const int t = threadIdx.x;
    const int beg = bbase[b], end = bbase[b + 1];
    if (t < NPB) cnt[t] = 0;
    __syncthreads();
    for (int i = beg + t; i < end; i += 256)
        atomicAdd(&cnt[pairs[i] >> 17], 1);
    __syncthreads();
    int v = 0, x = 0;
    const int lane = t & 63, w = t >> 6;
    if (t < NPB) {
        v = cnt[t];
        x = v;
#pragma unroll
        for (int off = 1; off < 64; off <<= 1) {
            int y = __shfl_up(x, off);
            if (lane >= off) x += y;
        }
        if (t == 63) wtot = x;
    }
    __syncthreads();
    if (t < NPB) {
        const int gp = beg + (x - v) + (w ? wtot : 0);
        cur[t] = gp;
        nptr[b * NPB + t] = gp;
    }
    if (b == NB - 1 && t == 255) nptr[NB * NPB] = end;
    __syncthreads();
    for (int i = beg + t; i < end; i += 256) {
        const int p = pairs[i];
        const int pos = atomicAdd(&cur[p >> 17], 1);
        csr[pos] = p & 0x1FFFF;
    }
}

// ---------------------------------------------------------------------------
// Aggregation + fused rrelu: one wave per dst node, lane = column.
// Gathers bf16 h rows (12.8 MB -> L2/L3-resident), f32 accumulate,
// writes each output row exactly once.
// ---------------------------------------------------------------------------
__global__ __launch_bounds__(256) void agg_rrelu_kernel(const ushort* __restrict__ h,
                                                        const int* __restrict__ csr,
                                                        const int* __restrict__ nptr,
                                                        float* __restrict__ out) {
    const int node = blockIdx.x * 4 + (threadIdx.x >> 6);  // 100000 % 4 == 0
    const int c = threadIdx.x & 63;
    const int beg = nptr[node], end = nptr[node + 1];
    float acc = 0.f;
    int i = beg;
    for (; i + 4 <= end; i += 4) {
        const int s0 = csr[i], s1 = csr[i + 1], s2 = csr[i + 2], s3 = csr[i + 3];
        const float v0 = bf2f(h[(size_t)s0 * OUT_FEAT + c]);
        const float v1 = bf2f(h[(size_t)s1 * OUT_FEAT + c]);
        const float v2 = bf2f(h[(size_t)s2 * OUT_FEAT + c]);
        const float v3 = bf2f(h[(size_t)s3 * OUT_FEAT + c]);
        acc += v0 + v1 + v2 + v3;
    }
    for (; i < end; ++i) acc += bf2f(h[(size_t)csr[i] * OUT_FEAT + c]);
    acc = acc >= 0.f ? acc : acc * SLOPE;
    out[(size_t)node * OUT_FEAT + c] = acc;
}

// ---------------------------------------------------------------------------
// GEMM1: feat[N,128] @ w1[128,64] -> bf16 h. 16 rows/block, 4 rows/thread.
// ---------------------------------------------------------------------------
__global__ __launch_bounds__(256) void gemm1_kernel(const float* __restrict__ feat,
                                                    const float* __restrict__ w1,
                                                    ushort* __restrict__ h1) {
    __shared__ float w[IN_FEAT * OUT_FEAT];  // 32 KB
    __shared__ float f[16 * IN_FEAT];        // 8 KB
    const int tid = threadIdx.x;

    const float4* w4 = (const float4*)w1;
    float4* wl = (float4*)w;
#pragma unroll
    for (int i = 0; i < 8; ++i) wl[tid + i * 256] = w4[tid + i * 256];

    const int row0 = blockIdx.x * 16;
    const float4* fg = (const float4*)(feat + (size_t)row0 * IN_FEAT);
    float4* fl = (float4*)f;
#pragma unroll
    for (int i = 0; i < 2; ++i) fl[tid + i * 256] = fg[tid + i * 256];
    __syncthreads();

    const int c = tid & 63;
    const int rg = tid >> 6;
    float acc0 = 0.f, acc1 = 0.f, acc2 = 0.f, acc3 = 0.f;
    const float4* fv = (const float4*)f;
#pragma unroll
    for (int k = 0; k < IN_FEAT; k += 4) {
        const float wa = w[(k + 0) * OUT_FEAT + c];
        const float wb = w[(k + 1) * OUT_FEAT + c];
        const float wc = w[(k + 2) * OUT_FEAT + c];
        const float wd = w[(k + 3) * OUT_FEAT + c];
        float4 a = fv[((rg * 4 + 0) * IN_FEAT + k) >> 2];
        acc0 += a.x * wa + a.y * wb + a.z * wc + a.w * wd;
        float4 bb = fv[((rg * 4 + 1) * IN_FEAT + k) >> 2];
        acc1 += bb.x * wa + bb.y * wb + bb.z * wc + bb.w * wd;
        float4 d = fv[((rg * 4 + 2) * IN_FEAT + k) >> 2];
        acc2 += d.x * wa + d.y * wb + d.z * wc + d.w * wd;
        float4 e = fv[((rg * 4 + 3) * IN_FEAT + k) >> 2];
        acc3 += e.x * wa + e.y * wb + e.z * wc + e.w * wd;
    }
    h1[(size_t)(row0 + rg * 4 + 0) * OUT_FEAT + c] = f2bf(acc0);
    h1[(size_t)(row0 + rg * 4 + 1) * OUT_FEAT + c] = f2bf(acc1);
    h1[(size_t)(row0 + rg * 4 + 2) * OUT_FEAT + c] = f2bf(acc2);
    h1[(size_t)(row0 + rg * 4 + 3) * OUT_FEAT + c] = f2bf(acc3);
}

// ---------------------------------------------------------------------------
// GEMM2: agg1[N,64] (f32, already rrelu'd) @ w2[64,64] -> bf16 h.
// ---------------------------------------------------------------------------
__global__ __launch_bounds__(256) void gemm2_kernel(const float* __restrict__ agg1,
                                                    const float* __restrict__ w2,
                                                    ushort* __restrict__ h2) {
    __shared__ float w[OUT_FEAT * OUT_FEAT];  // 16 KB
    __shared__ float f[16 * OUT_FEAT];        // 4 KB
    const int tid = threadIdx.x;

    const float4* w4 = (const float4*)w2;
    float4* wl = (float4*)w;
#pragma unroll
    for (int i = 0; i < 4; ++i) wl[tid + i * 256] = w4[tid + i * 256];

    const int row0 = blockIdx.x * 16;
    const float4* fg = (const float4*)(agg1 + (size_t)row0 * OUT_FEAT);
    ((float4*)f)[tid] = fg[tid];
    __syncthreads();

    const int c = tid & 63;
    const int rg = tid >> 6;
    float acc0 = 0.f, acc1 = 0.f, acc2 = 0.f, acc3 = 0.f;
    const float4* fv = (const float4*)f;
#pragma unroll
    for (int k = 0; k < OUT_FEAT; k += 4) {
        const float wa = w[(k + 0) * OUT_FEAT + c];
        const float wb = w[(k + 1) * OUT_FEAT + c];
        const float wc = w[(k + 2) * OUT_FEAT + c];
        const float wd = w[(k + 3) * OUT_FEAT + c];
        float4 a = fv[((rg * 4 + 0) * OUT_FEAT + k) >> 2];
        acc0 += a.x * wa + a.y * wb + a.z * wc + a.w * wd;
        float4 bb = fv[((rg * 4 + 1) * OUT_FEAT + k) >> 2];
        acc1 += bb.x * wa + bb.y * wb + bb.z * wc + bb.w * wd;
        float4 d = fv[((rg * 4 + 2) * OUT_FEAT + k) >> 2];
        acc2 += d.x * wa + d.y * wb + d.z * wc + d.w * wd;
        float4 e = fv[((rg * 4 + 3) * OUT_FEAT + k) >> 2];
        acc3 += e.x * wa + e.y * wb + e.z * wc + e.w * wd;
    }
    h2[(size_t)(row0 + rg * 4 + 0) * OUT_FEAT + c] = f2bf(acc0);
    h2[(size_t)(row0 + rg * 4 + 1) * OUT_FEAT + c] = f2bf(acc1);
    h2[(size_t)(row0 + rg * 4 + 2) * OUT_FEAT + c] = f2bf(acc2);
    h2[(size_t)(row0 + rg * 4 + 3) * OUT_FEAT + c] = f2bf(acc3);
}

extern "C" void kernel_launch(void* const* d_in, const int* in_sizes, int n_in,
                              void* d_out, int out_size, void* d_ws, size_t ws_size,
                              hipStream_t stream) {
    const float* feat = (const float*)d_in[0];
    const int*   src  = (const int*)d_in[1];
    const int*   dst  = (const int*)d_in[2];
    const float* w1   = (const float*)d_in[3];
    const float* w2   = (const float*)d_in[4];
    float* out = (float*)d_out;

    // workspace layout
    ushort* h     = (ushort*)d_ws;                           // 12.8 MB
    int*    pairs = (int*)(h + (size_t)N_NODES * OUT_FEAT);  // 6.4 MB
    int*    csr   = pairs + N_EDGES;                         // 6.4 MB
    int*    nptr  = csr + N_EDGES;                           // NB*NPB+1
    int*    bhist = nptr + NB * NPB + 1;                     // NB
    int*    bbase = bhist + NB;                              // NB+1
    int*    bcur  = bbase + NB + 1;                          // NB

    // ---- build by-dst CSR (once; reused for both layers) ----
    hipMemsetAsync(bhist, 0, NB * sizeof(int), stream);
    bhist_kernel<<<(N_EDGES + 2047) / 2048, 256, 0, stream>>>(dst, bhist);
    bscan_kernel<<<1, 256, 0, stream>>>(bhist, bbase, bcur);
    binning_kernel<<<(N_EDGES + BIN_CHUNK - 1) / BIN_CHUNK, 256, 0, stream>>>(
        src, dst, bcur, pairs);
    sort2_kernel<<<NB, 256, 0, stream>>>(pairs, bbase, csr, nptr);

    // ---- layer 1 ----
    gemm1_kernel<<<N_NODES / 16, 256, 0, stream>>>(feat, w1, h);
    agg_rrelu_kernel<<<N_NODES / 4, 256, 0, stream>>>(h, csr, nptr, out);

    // ---- layer 2 ----
    gemm2_kernel<<<N_NODES / 16, 256, 0, stream>>>(out, w2, h);
    agg_rrelu_kernel<<<N_NODES / 4, 256, 0, stream>>>(h, csr, nptr, out);
}

// Round 5
// 249.344 us; speedup vs baseline: 6.0197x; 1.0751x over previous
//
#include <hip/hip_runtime.h>

#define N_NODES 100000
#define N_EDGES 1600000
#define IN_FEAT 128
#define OUT_FEAT 64
#define SLOPE 0.22916666666666666f  // (1/8 + 1/3)/2 = 11/48

#define NPB 128            // nodes per bucket
#define NB 782             // ceil(N_NODES / NPB)
#define BIN_CHUNK 8192     // edges per binning block
#define EPT 32             // edges per thread in binning (BIN_CHUNK/256)

__device__ __forceinline__ ushort f2bf(float x) {
    unsigned u = __float_as_uint(x);
    u += 0x7FFFu + ((u >> 16) & 1u);  // round to nearest even
    return (ushort)(u >> 16);
}
__device__ __forceinline__ float bf2f(ushort v) {
    return __uint_as_float((unsigned)v << 16);
}

// ---------------------------------------------------------------------------
// Bucket histogram: LDS-binned per block, one global atomic per bucket/block.
// ---------------------------------------------------------------------------
__global__ __launch_bounds__(256) void bhist_kernel(const int* __restrict__ dst,
                                                    int* __restrict__ bhist) {
    __shared__ int lh[NB];
    for (int i = threadIdx.x; i < NB; i += 256) lh[i] = 0;
    __syncthreads();
    const int base = blockIdx.x * 2048;
#pragma unroll
    for (int i = 0; i < 8; ++i) {
        const int e = base + i * 256 + threadIdx.x;
        if (e < N_EDGES) atomicAdd(&lh[dst[e] >> 7], 1);
    }
    __syncthreads();
    for (int i = threadIdx.x; i < NB; i += 256)
        if (lh[i]) atomicAdd(&bhist[i], lh[i]);
}

// ---------------------------------------------------------------------------
// Exclusive scan of 782 bucket counts (single block) -> bbase[NB+1], bcur.
// ---------------------------------------------------------------------------
__global__ __launch_bounds__(256) void bscan_kernel(const int* __restrict__ bhist,
                                                    int* __restrict__ bbase,
                                                    int* __restrict__ bcur) {
    __shared__ int wsum[4];
    const int t = threadIdx.x;
    int v[4];
    int s = 0;
#pragma unroll
    for (int i = 0; i < 4; ++i) {
        const int idx = t * 4 + i;
        v[i] = s;
        s += (idx < NB) ? bhist[idx] : 0;
    }
    const int lane = t & 63, wave = t >> 6;
    int x = s;
#pragma unroll
    for (int off = 1; off < 64; off <<= 1) {
        int y = __shfl_up(x, off);
        if (lane >= off) x += y;
    }
    if (lane == 63) wsum[wave] = x;
    __syncthreads();
    int wbase = 0;
    for (int w = 0; w < 4; ++w)
        if (w < wave) wbase += wsum[w];
    const int tbase = wbase + x - s;
#pragma unroll
    for (int i = 0; i < 4; ++i) {
        const int idx = t * 4 + i;
        if (idx < NB) {
            bbase[idx] = tbase + v[i];
            bcur[idx]  = tbase + v[i];
        }
    }
    if (t == 255) bbase[NB] = wbase + x;  // == N_EDGES
}

// ---------------------------------------------------------------------------
// Binning pass 1: dense per-block runs of packed ((dst&127)<<17 | src).
// ---------------------------------------------------------------------------
__global__ __launch_bounds__(256) void binning_kernel(const int* __restrict__ src,
                                                      const int* __restrict__ dst,
                                                      int* __restrict__ bcur,
                                                      int* __restrict__ pairs) {
    __shared__ int cnt[NB];
    __shared__ int gbase[NB];
    for (int i = threadIdx.x; i < NB; i += 256) cnt[i] = 0;
    __syncthreads();
    const int base = blockIdx.x * BIN_CHUNK;
    int bl[EPT];
    int vp[EPT];
#pragma unroll
    for (int i = 0; i < EPT; ++i) {
        const int e = base + i * 256 + threadIdx.x;
        if (e < N_EDGES) {
            const int d = dst[e];
            const int b = d >> 7;
            const int lpos = atomicAdd(&cnt[b], 1);
            bl[i] = (b << 13) | lpos;
            vp[i] = ((d & 127) << 17) | src[e];
        } else {
            bl[i] = -1;
        }
    }
    __syncthreads();
    for (int i = threadIdx.x; i < NB; i += 256) {
        const int c = cnt[i];
        gbase[i] = c ? atomicAdd(&bcur[i], c) : 0;
    }
    __syncthreads();
#pragma unroll
    for (int i = 0; i < EPT; ++i) {
        if (bl[i] >= 0) {
            const int b = bl[i] >> 13, lpos = bl[i] & 8191;
            pairs[gbase[b] + lpos] = vp[i];
        }
    }
}

// ---------------------------------------------------------------------------
// Binning pass 2: per-bucket counting sort -> per-node CSR segments.
// ---------------------------------------------------------------------------
__global__ __launch_bounds__(256) void sort2_kernel(const int* __restrict__ pairs,
                                                    const int* __restrict__ bbase,
                                                    int* __restrict__ csr,
                                                    int* __restrict__ nptr) {
    __shared__ int cnt[NPB];
    __shared__ int cur[NPB];
    __shared__ int wtot;
    const int b = blockIdx.x;
    const int t = threadIdx.x;
    const int beg = bbase[b], end = bbase[b + 1];
    if (t < NPB) cnt[t] = 0;
    __syncthreads();
    for (int i = beg + t; i < end; i += 256)
        atomicAdd(&cnt[pairs[i] >> 17], 1);
    __syncthreads();
    int v = 0, x = 0;
    const int lane = t & 63, w = t >> 6;
    if (t < NPB) {
        v = cnt[t];
        x = v;
#pragma unroll
        for (int off = 1; off < 64; off <<= 1) {
            int y = __shfl_up(x, off);
            if (lane >= off) x += y;
        }
        if (t == 63) wtot = x;
    }
    __syncthreads();
    if (t < NPB) {
        const int gp = beg + (x - v) + (w ? wtot : 0);
        cur[t] = gp;
        nptr[b * NPB + t] = gp;
    }
    if (b == NB - 1 && t == 255) nptr[NB * NPB] = end;
    __syncthreads();
    for (int i = beg + t; i < end; i += 256) {
        const int p = pairs[i];
        const int pos = atomicAdd(&cur[p >> 17], 1);
        csr[pos] = p & 0x1FFFF;
    }
}

// gather-accumulate helpers: 8-deep / 4-deep unrolled batches for MLP
#define GATHER8(acc)                                                        \
    {                                                                       \
        const int s0 = csr[i], s1 = csr[i + 1], s2 = csr[i + 2],            \
                  s3 = csr[i + 3], s4 = csr[i + 4], s5 = csr[i + 5],        \
                  s6 = csr[i + 6], s7 = csr[i + 7];                         \
        const float v0 = bf2f(h[(size_t)s0 * OUT_FEAT + c]);                \
        const float v1 = bf2f(h[(size_t)s1 * OUT_FEAT + c]);                \
        const float v2 = bf2f(h[(size_t)s2 * OUT_FEAT + c]);                \
        const float v3 = bf2f(h[(size_t)s3 * OUT_FEAT + c]);                \
        const float v4 = bf2f(h[(size_t)s4 * OUT_FEAT + c]);                \
        const float v5 = bf2f(h[(size_t)s5 * OUT_FEAT + c]);                \
        const float v6 = bf2f(h[(size_t)s6 * OUT_FEAT + c]);                \
        const float v7 = bf2f(h[(size_t)s7 * OUT_FEAT + c]);                \
        acc += ((v0 + v1) + (v2 + v3)) + ((v4 + v5) + (v6 + v7));           \
    }

// ---------------------------------------------------------------------------
// Layer-1 fused: agg(h1) -> rrelu -> @w2 -> bf16 h2.
// One wave per node, lane = column. Row transposed through per-wave LDS
// buffer; w2 staged in LDS (16 KB). Writes h2 only (12.8 MB bf16).
// ---------------------------------------------------------------------------
__global__ __launch_bounds__(256) void agg_gemm2_kernel(const ushort* __restrict__ h,
                                                        const int* __restrict__ csr,
                                                        const int* __restrict__ nptr,
                                                        const float* __restrict__ w2,
                                                        ushort* __restrict__ h2) {
    __shared__ float w[OUT_FEAT * OUT_FEAT];  // 16 KB
    __shared__ float rowbuf[4][OUT_FEAT];     // 1 KB, one row per wave
    const int tid = threadIdx.x;

    const float4* w4g = (const float4*)w2;
    float4* wl = (float4*)w;
#pragma unroll
    for (int i = 0; i < 4; ++i) wl[tid + i * 256] = w4g[tid + i * 256];
    __syncthreads();

    const int wv = tid >> 6, c = tid & 63;
    const int node = blockIdx.x * 4 + wv;  // grid = 25000, all valid
    const int beg = nptr[node], end = nptr[node + 1];
    float acc = 0.f;
    int i = beg;
    for (; i + 8 <= end; i += 8) GATHER8(acc);
    if (i + 4 <= end) {
        const int s0 = csr[i], s1 = csr[i + 1], s2 = csr[i + 2], s3 = csr[i + 3];
        acc += (bf2f(h[(size_t)s0 * OUT_FEAT + c]) + bf2f(h[(size_t)s1 * OUT_FEAT + c])) +
               (bf2f(h[(size_t)s2 * OUT_FEAT + c]) + bf2f(h[(size_t)s3 * OUT_FEAT + c]));
        i += 4;
    }
    for (; i < end; ++i) acc += bf2f(h[(size_t)csr[i] * OUT_FEAT + c]);
    acc = acc >= 0.f ? acc : acc * SLOPE;

    // transpose row through LDS (intra-wave only; lgkmcnt ordering suffices,
    // __syncthreads also covers the w staging reuse)
    rowbuf[wv][c] = acc;
    __syncthreads();

    float o = 0.f;
    const float4* rb4 = (const float4*)rowbuf[wv];
#pragma unroll
    for (int k = 0; k < OUT_FEAT; k += 4) {
        const float4 r = rb4[k >> 2];  // wave-uniform broadcast
        o += r.x * w[(k + 0) * OUT_FEAT + c] + r.y * w[(k + 1) * OUT_FEAT + c] +
             r.z * w[(k + 2) * OUT_FEAT + c] + r.w * w[(k + 3) * OUT_FEAT + c];
    }
    h2[(size_t)node * OUT_FEAT + c] = f2bf(o);
}

// ---------------------------------------------------------------------------
// Layer-2 aggregation + fused rrelu -> f32 d_out. One wave per node.
// ---------------------------------------------------------------------------
__global__ __launch_bounds__(256) void agg_rrelu_kernel(const ushort* __restrict__ h,
                                                        const int* __restrict__ csr,
                                                        const int* __restrict__ nptr,
                                                        float* __restrict__ out) {
    const int node = blockIdx.x * 4 + (threadIdx.x >> 6);
    const int c = threadIdx.x & 63;
    const int beg = nptr[node], end = nptr[node + 1];
    float acc = 0.f;
    int i = beg;
    for (; i + 8 <= end; i += 8) GATHER8(acc);
    if (i + 4 <= end) {
        const int s0 = csr[i], s1 = csr[i + 1], s2 = csr[i + 2], s3 = csr[i + 3];
        acc += (bf2f(h[(size_t)s0 * OUT_FEAT + c]) + bf2f(h[(size_t)s1 * OUT_FEAT + c])) +
               (bf2f(h[(size_t)s2 * OUT_FEAT + c]) + bf2f(h[(size_t)s3 * OUT_FEAT + c]));
        i += 4;
    }
    for (; i < end; ++i) acc += bf2f(h[(size_t)csr[i] * OUT_FEAT + c]);
    acc = acc >= 0.f ? acc : acc * SLOPE;
    out[(size_t)node * OUT_FEAT + c] = acc;
}

// ---------------------------------------------------------------------------
// GEMM1: feat[N,128] @ w1[128,64] -> bf16 h. 16 rows/block, 4 rows/thread.
// ---------------------------------------------------------------------------
__global__ __launch_bounds__(256) void gemm1_kernel(const float* __restrict__ feat,
                                                    const float* __restrict__ w1,
                                                    ushort* __restrict__ h1) {
    __shared__ float w[IN_FEAT * OUT_FEAT];  // 32 KB
    __shared__ float f[16 * IN_FEAT];        // 8 KB
    const int tid = threadIdx.x;

    const float4* w4 = (const float4*)w1;
    float4* wl = (float4*)w;
#pragma unroll
    for (int i = 0; i < 8; ++i) wl[tid + i * 256] = w4[tid + i * 256];

    const int row0 = blockIdx.x * 16;
    const float4* fg = (const float4*)(feat + (size_t)row0 * IN_FEAT);
    float4* fl = (float4*)f;
#pragma unroll
    for (int i = 0; i < 2; ++i) fl[tid + i * 256] = fg[tid + i * 256];
    __syncthreads();

    const int c = tid & 63;
    const int rg = tid >> 6;
    float acc0 = 0.f, acc1 = 0.f, acc2 = 0.f, acc3 = 0.f;
    const float4* fv = (const float4*)f;
#pragma unroll
    for (int k = 0; k < IN_FEAT; k += 4) {
        const float wa = w[(k + 0) * OUT_FEAT + c];
        const float wb = w[(k + 1) * OUT_FEAT + c];
        const float wc = w[(k + 2) * OUT_FEAT + c];
        const float wd = w[(k + 3) * OUT_FEAT + c];
        float4 a = fv[((rg * 4 + 0) * IN_FEAT + k) >> 2];
        acc0 += a.x * wa + a.y * wb + a.z * wc + a.w * wd;
        float4 bb = fv[((rg * 4 + 1) * IN_FEAT + k) >> 2];
        acc1 += bb.x * wa + bb.y * wb + bb.z * wc + bb.w * wd;
        float4 d = fv[((rg * 4 + 2) * IN_FEAT + k) >> 2];
        acc2 += d.x * wa + d.y * wb + d.z * wc + d.w * wd;
        float4 e = fv[((rg * 4 + 3) * IN_FEAT + k) >> 2];
        acc3 += e.x * wa + e.y * wb + e.z * wc + e.w * wd;
    }
    h1[(size_t)(row0 + rg * 4 + 0) * OUT_FEAT + c] = f2bf(acc0);
    h1[(size_t)(row0 + rg * 4 + 1) * OUT_FEAT + c] = f2bf(acc1);
    h1[(size_t)(row0 + rg * 4 + 2) * OUT_FEAT + c] = f2bf(acc2);
    h1[(size_t)(row0 + rg * 4 + 3) * OUT_FEAT + c] = f2bf(acc3);
}

extern "C" void kernel_launch(void* const* d_in, const int* in_sizes, int n_in,
                              void* d_out, int out_size, void* d_ws, size_t ws_size,
                              hipStream_t stream) {
    const float* feat = (const float*)d_in[0];
    const int*   src  = (const int*)d_in[1];
    const int*   dst  = (const int*)d_in[2];
    const float* w1   = (const float*)d_in[3];
    const float* w2   = (const float*)d_in[4];
    float* out = (float*)d_out;

    // workspace layout
    ushort* h1    = (ushort*)d_ws;                            // 12.8 MB
    ushort* h2    = h1 + (size_t)N_NODES * OUT_FEAT;          // 12.8 MB
    int*    pairs = (int*)(h2 + (size_t)N_NODES * OUT_FEAT);  // 6.4 MB
    int*    csr   = pairs + N_EDGES;                          // 6.4 MB
    int*    nptr  = csr + N_EDGES;                            // NB*NPB+1
    int*    bhist = nptr + NB * NPB + 1;                      // NB
    int*    bbase = bhist + NB;                               // NB+1
    int*    bcur  = bbase + NB + 1;                           // NB

    // ---- build by-dst CSR (once; reused for both layers) ----
    hipMemsetAsync(bhist, 0, NB * sizeof(int), stream);
    bhist_kernel<<<(N_EDGES + 2047) / 2048, 256, 0, stream>>>(dst, bhist);
    bscan_kernel<<<1, 256, 0, stream>>>(bhist, bbase, bcur);
    binning_kernel<<<(N_EDGES + BIN_CHUNK - 1) / BIN_CHUNK, 256, 0, stream>>>(
        src, dst, bcur, pairs);
    sort2_kernel<<<NB, 256, 0, stream>>>(pairs, bbase, csr, nptr);

    // ---- layer 1 (gemm2 fused into aggregation) ----
    gemm1_kernel<<<N_NODES / 16, 256, 0, stream>>>(feat, w1, h1);
    agg_gemm2_kernel<<<N_NODES / 4, 256, 0, stream>>>(h1, csr, nptr, w2, h2);

    // ---- layer 2 ----
    agg_rrelu_kernel<<<N_NODES / 4, 256, 0, stream>>>(h2, csr, nptr, out);
}